// Round 2
// baseline (289.620 us; speedup 1.0000x reference)
//
#include <hip/hip_runtime.h>
#include <hip/hip_bf16.h>

// QuantizedLinear: out[64,11008] = x[64,4096] @ (Wq*scale)^T + bias
// Memory-bound on the 180 MB int32 weight stream. Design: barrier-free
// streaming GEMM (no LDS, no atomics), x pre-converted to bf16 in ws.

#define M_DIM 64
#define N_DIM 11008
#define K_DIM 4096
#define KSPLIT 4
#define KC (K_DIM / KSPLIT)          // 1024
#define OUT_ELEMS (M_DIM * N_DIM)    // 704512

typedef __attribute__((ext_vector_type(8))) short bf16x8;
typedef __attribute__((ext_vector_type(4))) float f32x4;
typedef __attribute__((ext_vector_type(4))) int i32x4;
typedef __attribute__((ext_vector_type(8))) short s16x8;

// RNE float -> bf16
__device__ __forceinline__ short f2bf(float f) {
    unsigned int u = __builtin_bit_cast(unsigned int, f);
    u = u + 0x7FFFu + ((u >> 16) & 1u);
    return (short)(u >> 16);
}
// int in [-128,127] -> bf16 EXACT (≤8 significand bits)
__device__ __forceinline__ short i2bf(int q) {
    float f = (float)q;
    return (short)(__builtin_bit_cast(unsigned int, f) >> 16);
}

// ---- x [64][4096] f32 -> bf16 (row-major, same layout) into ws ----
__global__ __launch_bounds__(256) void convert_x_kernel(const float* __restrict__ x,
                                                        short* __restrict__ xs) {
    int idx = blockIdx.x * 256 + threadIdx.x;       // 32768 threads x 8 elems
    const f32x4* p = (const f32x4*)x + (size_t)idx * 2;
    f32x4 a = p[0], b = p[1];
    s16x8 h;
    h[0] = f2bf(a.x); h[1] = f2bf(a.y); h[2] = f2bf(a.z); h[3] = f2bf(a.w);
    h[4] = f2bf(b.x); h[5] = f2bf(b.y); h[6] = f2bf(b.z); h[7] = f2bf(b.w);
    *((s16x8*)xs + idx) = h;
}

// ---- barrier-free streaming GEMM: 1 wave/block, tile M64 x N16, K-split ----
// part[ks][m][n] = sum_{k in slice ks} x[m][k] * wq[n][k]   (unscaled)
__global__ __launch_bounds__(64) void qgemm_kernel(const short* __restrict__ xs,
                                                   const int* __restrict__ wq,
                                                   float* __restrict__ part) {
    const int lane = threadIdx.x;       // 0..63
    const int quad = lane >> 4;         // k-offset selector
    const int l16  = lane & 15;         // n (B) / m (A) within 16-tile
    const int n0   = blockIdx.x * 16;
    const int ks   = blockIdx.y;
    const int kc0  = ks * KC;

    // weight row for B fragment: B[n=l16][k=quad*8+j]
    const int* wrow = wq + (size_t)(n0 + l16) * K_DIM + kc0 + quad * 8;
    // x rows for A fragments: A[m=mi*16+l16][k=quad*8+j]
    const short* xrow = xs + (size_t)l16 * K_DIM + kc0 + quad * 8;

    f32x4 acc[4] = {f32x4{0,0,0,0}, f32x4{0,0,0,0}, f32x4{0,0,0,0}, f32x4{0,0,0,0}};

    #pragma unroll 4
    for (int kk = 0; kk < KC; kk += 32) {
        // weights: 8 consecutive int32 (32 B) per lane, nontemporal (read-once,
        // keep x resident in L2)
        i32x4 b0 = __builtin_nontemporal_load((const i32x4*)(wrow + kk));
        i32x4 b1 = __builtin_nontemporal_load((const i32x4*)(wrow + kk + 4));
        bf16x8 bfrag;
        bfrag[0] = i2bf(b0.x); bfrag[1] = i2bf(b0.y);
        bfrag[2] = i2bf(b0.z); bfrag[3] = i2bf(b0.w);
        bfrag[4] = i2bf(b1.x); bfrag[5] = i2bf(b1.y);
        bfrag[6] = i2bf(b1.z); bfrag[7] = i2bf(b1.w);

        #pragma unroll
        for (int mi = 0; mi < 4; ++mi) {
            bf16x8 afrag = *(const bf16x8*)(xrow + (size_t)mi * 16 * K_DIM + kk);
            acc[mi] = __builtin_amdgcn_mfma_f32_16x16x32_bf16(afrag, bfrag, acc[mi], 0, 0, 0);
        }
    }

    // epilogue: raw partial store (scale/bias applied in reduce)
    float* ps = part + (size_t)ks * OUT_ELEMS + n0 + l16;
    #pragma unroll
    for (int mi = 0; mi < 4; ++mi) {
        #pragma unroll
        for (int r = 0; r < 4; ++r) {
            int m = mi * 16 + quad * 4 + r;
            ps[(size_t)m * N_DIM] = acc[mi][r];
        }
    }
}

// ---- out = scale * sum_s part[s] + bias ----
__global__ __launch_bounds__(256) void reduce_kernel(const float* __restrict__ part,
                                                     const float* __restrict__ scale_p,
                                                     const float* __restrict__ bias,
                                                     float* __restrict__ out) {
    int i4 = blockIdx.x * 256 + threadIdx.x;        // 176128 f32x4 elems
    float s = *scale_p;
    int col4 = i4 % 2752;                           // N/4
    f32x4 b = *(const f32x4*)(bias + col4 * 4);
    f32x4 a0 = *((const f32x4*)part + i4);
    f32x4 a1 = *((const f32x4*)(part + (size_t)OUT_ELEMS) + i4);
    f32x4 a2 = *((const f32x4*)(part + (size_t)2 * OUT_ELEMS) + i4);
    f32x4 a3 = *((const f32x4*)(part + (size_t)3 * OUT_ELEMS) + i4);
    f32x4 r;
    r.x = (a0.x + a1.x + a2.x + a3.x) * s + b.x;
    r.y = (a0.y + a1.y + a2.y + a3.y) * s + b.y;
    r.z = (a0.z + a1.z + a2.z + a3.z) * s + b.z;
    r.w = (a0.w + a1.w + a2.w + a3.w) * s + b.w;
    *((f32x4*)out + i4) = r;
}

extern "C" void kernel_launch(void* const* d_in, const int* in_sizes, int n_in,
                              void* d_out, int out_size, void* d_ws, size_t ws_size,
                              hipStream_t stream) {
    const float* x     = (const float*)d_in[0];
    const int*   wq    = (const int*)d_in[1];
    const float* scale = (const float*)d_in[2];
    const float* bias  = (const float*)d_in[3];
    float* out = (float*)d_out;

    float* part = (float*)d_ws;                                    // 4 * 704512 f32 = 11.3 MB
    short* xs   = (short*)((char*)d_ws + (size_t)KSPLIT * OUT_ELEMS * 4);  // 512 KB, 16B-aligned

    // 1) x -> bf16
    convert_x_kernel<<<128, 256, 0, stream>>>(x, xs);

    // 2) streaming GEMM, K-split partials
    dim3 grid(N_DIM / 16, KSPLIT);   // (688, 4) x 64 threads
    qgemm_kernel<<<grid, 64, 0, stream>>>(xs, wq, part);

    // 3) reduce + scale + bias
    reduce_kernel<<<688, 256, 0, stream>>>(part, scale, bias, out);
}

// Round 3
// 271.504 us; speedup vs baseline: 1.0667x; 1.0667x over previous
//
#include <hip/hip_runtime.h>
#include <hip/hip_bf16.h>

// QuantizedLinear: out[64,11008] = x[64,4096] @ (Wq*scale)^T + bias
// HBM-bound on the 180 MB int32 weight stream. Round 3: memcpy-shaped
// streaming via global_load_lds (contiguous 1KB/wave/instr), double-buffered
// LDS with raw s_barrier + manual vmcnt so prefetch stays in flight.

#define M_DIM 64
#define N_DIM 11008
#define K_DIM 4096
#define KSPLIT 8
#define KC (K_DIM / KSPLIT)          // 512
#define BK 64
#define NIT (KC / BK)                // 8
#define OUT_ELEMS (M_DIM * N_DIM)    // 704512

#define WBYTES (64 * BK * 4)         // 16 KB weights (int32) per buffer
#define XBYTES (64 * BK * 2)         // 8 KB x (bf16) per buffer
#define BUFBYTES (WBYTES + XBYTES)   // 24 KB

typedef __attribute__((ext_vector_type(8))) short bf16x8;
typedef __attribute__((ext_vector_type(4))) float f32x4;
typedef __attribute__((ext_vector_type(4))) int i32x4;
typedef __attribute__((ext_vector_type(8))) short s16x8;

// RNE float -> bf16
__device__ __forceinline__ short f2bf(float f) {
    unsigned int u = __builtin_bit_cast(unsigned int, f);
    u = u + 0x7FFFu + ((u >> 16) & 1u);
    return (short)(u >> 16);
}
// int in [-128,127] -> bf16 EXACT
__device__ __forceinline__ short i2bf(int q) {
    float f = (float)q;
    return (short)(__builtin_bit_cast(unsigned int, f) >> 16);
}

// global -> LDS direct copy, 16 B per lane. LDS dest resolves to
// (first-active-lane value) + lane*16, which equals our per-thread t*16 layout.
__device__ __forceinline__ void gload_lds(const void* g, void* l) {
    __builtin_amdgcn_global_load_lds(
        (const __attribute__((address_space(1))) unsigned int*)g,
        (__attribute__((address_space(3))) unsigned int*)l,
        16, 0, 0);
}

// ---- x [64][4096] f32 -> bf16 into ws ----
__global__ __launch_bounds__(256) void convert_x_kernel(const float* __restrict__ x,
                                                        short* __restrict__ xs) {
    int idx = blockIdx.x * 256 + threadIdx.x;   // 32768 threads x 8 elems
    const f32x4* p = (const f32x4*)x + (size_t)idx * 2;
    f32x4 a = p[0], b = p[1];
    s16x8 h;
    h[0] = f2bf(a.x); h[1] = f2bf(a.y); h[2] = f2bf(a.z); h[3] = f2bf(a.w);
    h[4] = f2bf(b.x); h[5] = f2bf(b.y); h[6] = f2bf(b.z); h[7] = f2bf(b.w);
    *((s16x8*)xs + idx) = h;
}

// ---- streaming GEMM: 256 thr / 4 waves, tile M64 x N64, K-split ----
__global__ __launch_bounds__(256) void qgemm_kernel(const short* __restrict__ xs,
                                                    const int* __restrict__ wq,
                                                    float* __restrict__ part) {
    __shared__ char smem[2 * BUFBYTES];          // 48 KB -> 3 blocks/CU

    const int t    = threadIdx.x;
    const int wav  = t >> 6;
    const int lane = t & 63;
    const int quad = lane >> 4;
    const int l16  = lane & 15;
    const int n0   = blockIdx.x * 64;
    const int ks   = blockIdx.y;
    const int kc0  = ks * KC;

    // --- staging source addressing (XOR chunk swizzle, same line footprint) ---
    // weights: instr j covers rows j*16+(t>>4), 16B chunk (t&15)^(row&15)
    const int wrow4 = t >> 4;                    // 0..15 (== row&15)
    const int wch   = (t & 15) ^ wrow4;
    const int* wsrc = wq + (size_t)(n0 + wrow4) * K_DIM + kc0 + wch * 4;
    // x: instr j covers m = j*32+(t>>3), 16B chunk (t&7)^(m&7)
    const int xm  = t >> 3;                      // 0..31 (m&7 == xm&7)
    const int xch = (t & 7) ^ (xm & 7);
    const short* xsrc = xs + (size_t)xm * K_DIM + kc0 + xch * 8;

    char* const wsl = smem + t * 16;             // + buf*BUFBYTES + j*4096
    char* const xsl = smem + WBYTES + t * 16;

    auto stage = [&](int buf, int kb) {
        char* wl = wsl + buf * BUFBYTES;
        char* xl = xsl + buf * BUFBYTES;
        #pragma unroll
        for (int j = 0; j < 4; ++j)
            gload_lds(wsrc + (size_t)j * 16 * K_DIM + kb, wl + j * 4096);
        #pragma unroll
        for (int j = 0; j < 2; ++j)
            gload_lds(xsrc + (size_t)j * 32 * K_DIM + kb, xl + j * 4096);
    };

    f32x4 acc[4] = {f32x4{0,0,0,0}, f32x4{0,0,0,0}, f32x4{0,0,0,0}, f32x4{0,0,0,0}};

    const int wrow = wav * 16 + l16;             // this wave's weight row in tile

    stage(0, 0);
    for (int it = 0; it < NIT; ++it) {
        if (it + 1 < NIT) {
            stage((it + 1) & 1, (it + 1) * BK);
            __atomic_signal_fence(__ATOMIC_SEQ_CST);
            __builtin_amdgcn_s_waitcnt(0x0F76);  // vmcnt(6): stage(it) done, prefetch flying
        } else {
            __atomic_signal_fence(__ATOMIC_SEQ_CST);
            __builtin_amdgcn_s_waitcnt(0x0F70);  // vmcnt(0): last stage done
        }
        __builtin_amdgcn_s_barrier();
        __atomic_signal_fence(__ATOMIC_SEQ_CST);

        const int*   wl = (const int*)(smem + (it & 1) * BUFBYTES);
        const short* xl = (const short*)(smem + (it & 1) * BUFBYTES + WBYTES);

        #pragma unroll
        for (int kk = 0; kk < BK; kk += 32) {
            const int c0 = kk / 4 + quad * 2;    // 16B chunk of this lane's k-slice
            i32x4 w0 = *(const i32x4*)(wl + wrow * 64 + ((c0 ^ l16) * 4));
            i32x4 w1 = *(const i32x4*)(wl + wrow * 64 + (((c0 + 1) ^ l16) * 4));
            bf16x8 bfrag;
            bfrag[0] = i2bf(w0.x); bfrag[1] = i2bf(w0.y);
            bfrag[2] = i2bf(w0.z); bfrag[3] = i2bf(w0.w);
            bfrag[4] = i2bf(w1.x); bfrag[5] = i2bf(w1.y);
            bfrag[6] = i2bf(w1.z); bfrag[7] = i2bf(w1.w);

            const int cx = kk / 8 + quad;        // x 16B chunk index (8 bf16)
            #pragma unroll
            for (int mi = 0; mi < 4; ++mi) {
                const int m = mi * 16 + l16;
                bf16x8 afrag = *(const bf16x8*)(xl + m * 64 + ((cx ^ (l16 & 7)) * 8));
                acc[mi] = __builtin_amdgcn_mfma_f32_16x16x32_bf16(afrag, bfrag, acc[mi], 0, 0, 0);
            }
        }

        __atomic_signal_fence(__ATOMIC_SEQ_CST);
        __builtin_amdgcn_s_barrier();            // reads of buf[it&1] done before re-stage
        __atomic_signal_fence(__ATOMIC_SEQ_CST);
    }

    // ---- epilogue: raw partials (scale/bias in reduce) ----
    float* ps = part + (size_t)ks * OUT_ELEMS + n0 + wav * 16 + l16;
    #pragma unroll
    for (int mi = 0; mi < 4; ++mi) {
        #pragma unroll
        for (int r = 0; r < 4; ++r) {
            int m = mi * 16 + quad * 4 + r;
            ps[(size_t)m * N_DIM] = acc[mi][r];
        }
    }
}

// ---- out = scale * sum_s part[s] + bias ----
__global__ __launch_bounds__(256) void reduce_kernel(const float* __restrict__ part,
                                                     const float* __restrict__ scale_p,
                                                     const float* __restrict__ bias,
                                                     float* __restrict__ out) {
    int i4 = blockIdx.x * 256 + threadIdx.x;     // 176128 f32x4
    float s = *scale_p;
    int col4 = i4 % 2752;                        // N/4
    f32x4 b = *(const f32x4*)(bias + col4 * 4);
    f32x4 a = *((const f32x4*)part + i4);
    #pragma unroll
    for (int sl = 1; sl < KSPLIT; ++sl) {
        f32x4 c = *((const f32x4*)(part + (size_t)sl * OUT_ELEMS) + i4);
        a.x += c.x; a.y += c.y; a.z += c.z; a.w += c.w;
    }
    f32x4 r;
    r.x = a.x * s + b.x; r.y = a.y * s + b.y;
    r.z = a.z * s + b.z; r.w = a.w * s + b.w;
    *((f32x4*)out + i4) = r;
}

extern "C" void kernel_launch(void* const* d_in, const int* in_sizes, int n_in,
                              void* d_out, int out_size, void* d_ws, size_t ws_size,
                              hipStream_t stream) {
    const float* x     = (const float*)d_in[0];
    const int*   wq    = (const int*)d_in[1];
    const float* scale = (const float*)d_in[2];
    const float* bias  = (const float*)d_in[3];
    float* out = (float*)d_out;

    float* part = (float*)d_ws;                                   // 8*704512*4 = 22.5 MB
    short* xs   = (short*)((char*)d_ws + (size_t)KSPLIT * OUT_ELEMS * 4);  // 512 KB

    convert_x_kernel<<<128, 256, 0, stream>>>(x, xs);

    dim3 grid(N_DIM / 64, KSPLIT);   // (172, 8)
    qgemm_kernel<<<grid, 256, 0, stream>>>(xs, wq, part);

    reduce_kernel<<<688, 256, 0, stream>>>(part, scale, bias, out);
}